// Round 9
// baseline (544.105 us; speedup 1.0000x reference)
//
#include <hip/hip_runtime.h>
#include <hip/hip_bf16.h>
#include <stdint.h>

#define T_TOK 131072
#define DIM   512
#define NBR   8
#define WIN   512                 // tokens per window
#define NWIN  (T_TOK / WIN)       // 256
#define SLCAP 640                 // padded slot capacity (40 slices of 16)
#define NSL   40
#define BK    32
#define NKT   (DIM / BK)          // 16

typedef __attribute__((ext_vector_type(8))) __bf16 bf16x8;
typedef __attribute__((ext_vector_type(4))) float  f32x4;
typedef unsigned short ushort_t;

__device__ __forceinline__ unsigned short f2bf(float f) {
  union { float f; unsigned int u; } v; v.f = f;
  unsigned int r = v.u + 0x7fffu + ((v.u >> 16) & 1u);
  return (unsigned short)(r >> 16);
}
__device__ __forceinline__ float bf2f(unsigned short u) {
  union { unsigned int i; float f; } v; v.i = ((unsigned int)u) << 16; return v.f;
}

// ---------- W transpose: (N,D,D) f32 -> Wt bf16 [b][kt][col][kk] ----------
__global__ __launch_bounds__(256) void k_wtrans(const float* __restrict__ W,
                                                ushort_t* __restrict__ Wt) {
  __shared__ float tile[BK][129];
  int blk = blockIdx.x;          // 8 * 16 * 4 = 512 blocks
  int b  = blk >> 6;
  int kt = (blk >> 2) & 15;
  int cb = blk & 3;
  int t = threadIdx.x;
  #pragma unroll
  for (int i = 0; i < 4; ++i) {
    int idx4 = i * 256 + t;
    int kr = idx4 >> 5;
    int c4 = idx4 & 31;
    const float* src = W + (((size_t)b * DIM + (size_t)(kt * BK + kr)) * DIM + cb * 128 + c4 * 4);
    float4 v = *(const float4*)src;
    tile[kr][c4 * 4 + 0] = v.x;
    tile[kr][c4 * 4 + 1] = v.y;
    tile[kr][c4 * 4 + 2] = v.z;
    tile[kr][c4 * 4 + 3] = v.w;
  }
  __syncthreads();
  int c  = t >> 1;
  int kh = t & 1;
  unsigned int p[8];
  #pragma unroll
  for (int i = 0; i < 8; ++i) {
    unsigned short lo = f2bf(tile[kh * 16 + i * 2 + 0][c]);
    unsigned short hi = f2bf(tile[kh * 16 + i * 2 + 1][c]);
    p[i] = (unsigned int)lo | ((unsigned int)hi << 16);
  }
  size_t obase = (((size_t)b * 16 + kt) * DIM + (size_t)(cb * 128 + c)) * BK + kh * 16;
  uint4 q0; q0.x = p[0]; q0.y = p[1]; q0.z = p[2]; q0.w = p[3];
  uint4 q1; q1.x = p[4]; q1.y = p[5]; q1.z = p[6]; q1.w = p[7];
  *(uint4*)&Wt[obase]     = q0;
  *(uint4*)&Wt[obase + 8] = q1;
}

// ---------- per-window local sort: smap, slice->branch, slice count ----------
__global__ __launch_bounds__(WIN) void k_sort(const int* __restrict__ bidx,
                                              unsigned short* __restrict__ smap,
                                              int* __restrict__ sliceBr,
                                              int* __restrict__ tsArr) {
  __shared__ int cnt[NBR], ps[NBR], rankL[WIN], bidL[WIN];
  const int w = blockIdx.x;
  const int t = threadIdx.x;
  if (t < NBR) cnt[t] = 0;
  __syncthreads();
  int b = bidx[w * WIN + t];
  bidL[t] = b;
  rankL[t] = atomicAdd(&cnt[b], 1);
  __syncthreads();
  if (t == 0) {
    int s = 0;
    for (int g = 0; g < NBR; ++g) { ps[g] = s; s += (cnt[g] + 15) >> 4; }
    tsArr[w] = s;
  }
  __syncthreads();
  if (t < NSL) {
    int br = -1;
    #pragma unroll
    for (int g = 0; g < NBR; ++g) {
      int sc = (cnt[g] + 15) >> 4;
      if (t >= ps[g] && t < ps[g] + sc) br = g;
    }
    sliceBr[w * NSL + t] = br;
  }
  smap[w * WIN + t] = (unsigned short)(ps[bidL[t]] * 16 + rankL[t]);
}

// ---------- x (f32, streaming read) -> xT bf16 [w][kt][slot][kk] ----------
__global__ __launch_bounds__(512) void k_xcvt(const float* __restrict__ x,
                                              const unsigned short* __restrict__ smap,
                                              ushort_t* __restrict__ xT, int w0) {
  __shared__ unsigned short slotL[WIN];
  const int bid = blockIdx.x;
  const int w = w0 + (bid >> 2);
  const int part = bid & 3;
  const int t = threadIdx.x;
  slotL[t] = smap[w * WIN + t];
  __syncthreads();
  const float4* xp = (const float4*)(x + (size_t)w * (WIN * DIM));
  ushort_t* xTw = xT + (size_t)(w - w0) * (NKT * SLCAP * BK);
  #pragma unroll 4
  for (int i = 0; i < 32; ++i) {
    int fidx = part * 16384 + i * 512 + t;       // float4 index within window
    float4 v = xp[fidx];
    int row = fidx >> 7;
    int kq4 = fidx & 127;
    int kt = kq4 >> 3;
    int kk = (kq4 & 7) * 4;
    int slot = slotL[row];
    ushort4 a4;
    a4.x = f2bf(v.x); a4.y = f2bf(v.y); a4.z = f2bf(v.z); a4.w = f2bf(v.w);
    *(ushort4*)&xTw[((size_t)kt * SLCAP + slot) * BK + kk] = a4;
  }
}

// ---------- GEMM: 512 thr, 8 waves = 2 rowgroups(4 slices) x 4 colgroups(64) ----------
// block = (window, col-half 256, slice-block of 8). A from L3-hot xT (1KB frags),
// B from L2-hot Wt (branch-run reload), out -> bf16 oT in slot order (cache-local).
// Regs: acc 64 + bq 32 + af 8 + misc ~20 <= 128 -> 2 blocks/CU, no spill.
__global__ __launch_bounds__(512, 4)
void k_gemm(const ushort_t* __restrict__ xT, const ushort_t* __restrict__ Wt,
            const float* __restrict__ bias,
            const int* __restrict__ sliceBr, const int* __restrict__ tsArr,
            ushort_t* __restrict__ oT, int w0) {
  __shared__ int sbrL[NSL];
  const int bid = blockIdx.x;
  const int wloc = bid / 10;
  const int r10 = bid - wloc * 10;
  const int cb = r10 & 1;               // col half (256)
  const int sb = r10 >> 1;              // slice-block 0..4 (8 slices each)
  const int w = w0 + wloc;
  const int t = threadIdx.x;
  const int l = t & 63;
  const int wv = t >> 6;
  const int ts = tsArr[w];
  if (t < NSL) sbrL[t] = sliceBr[w * NSL + t];
  __syncthreads();

  const int rg = wv >> 2;               // 0..1
  const int ch = wv & 3;                // 0..3
  const int colbase = cb * 256 + ch * 64;
  const int gs0 = sb * 8 + rg * 4;

  const ushort_t* xTw = xT + (size_t)wloc * (NKT * SLCAP * BK);
  const int aoff = (l & 15) * BK + (l >> 4) * 8;
  int boff[4];
  #pragma unroll
  for (int cf = 0; cf < 4; ++cf)
    boff[cf] = (colbase + cf * 16 + (l & 15)) * BK + (l >> 4) * 8;

  f32x4 acc[4][4];
  #pragma unroll
  for (int s = 0; s < 4; ++s)
    #pragma unroll
    for (int cf = 0; cf < 4; ++cf) acc[s][cf] = (f32x4){0.f, 0.f, 0.f, 0.f};

  for (int kt = 0; kt < NKT; ++kt) {
    const ushort_t* aplane = xTw + (size_t)kt * (SLCAP * BK);
    int curbr = -1;
    bf16x8 bq[4];
    #pragma unroll
    for (int s = 0; s < 4; ++s) {
      const int gs = gs0 + s;
      if (gs < ts) {
        int br = sbrL[gs];
        if (br != curbr) {
          curbr = br;
          const ushort_t* wp = Wt + ((size_t)br * NKT + kt) * (DIM * BK);
          #pragma unroll
          for (int cf = 0; cf < 4; ++cf) bq[cf] = *(const bf16x8*)(wp + boff[cf]);
        }
        bf16x8 af = *(const bf16x8*)(aplane + gs * 512 + aoff);
        #pragma unroll
        for (int cf = 0; cf < 4; ++cf)
          acc[s][cf] = __builtin_amdgcn_mfma_f32_16x16x32_bf16(af, bq[cf], acc[s][cf], 0, 0, 0);
      }
    }
  }

  // epilogue: bias + bf16 -> oT[slot][col] (slot-ordered, L2/L3-local)
  ushort_t* oTw = oT + (size_t)wloc * (SLCAP * DIM);
  #pragma unroll
  for (int s = 0; s < 4; ++s) {
    const int gs = gs0 + s;
    if (gs >= ts) continue;
    const int br = sbrL[gs];
    float bv[4];
    #pragma unroll
    for (int cf = 0; cf < 4; ++cf)
      bv[cf] = bias[br * DIM + colbase + cf * 16 + (l & 15)];
    #pragma unroll
    for (int j = 0; j < 4; ++j) {
      const int slot = gs * 16 + (l >> 4) * 4 + j;
      ushort_t* orow = oTw + (size_t)slot * DIM + colbase + (l & 15);
      #pragma unroll
      for (int cf = 0; cf < 4; ++cf)
        orow[cf * 16] = f2bf(acc[s][cf][j] + bv[cf]);
    }
  }
}

// ---------- oT (slot order, L3-hot gather) -> out (natural order, sequential) ----------
__global__ __launch_bounds__(512) void k_ocvt(const ushort_t* __restrict__ oT,
                                              const unsigned short* __restrict__ smap,
                                              float* __restrict__ out, int w0) {
  const int bid = blockIdx.x;           // WC*8 blocks, 64 rows each
  const int wloc = bid >> 3;
  const int rb = bid & 7;
  const int w = w0 + wloc;
  const int t = threadIdx.x;
  const int rloc = t >> 3;              // 0..63
  const int kq = t & 7;                 // 64-col segment
  const int row = rb * 64 + rloc;
  const int slot = smap[w * WIN + row];
  const ushort_t* src = oT + (size_t)wloc * (SLCAP * DIM) + (size_t)slot * DIM + kq * 64;
  float* dst = out + ((size_t)w * WIN + row) * DIM + kq * 64;
  #pragma unroll
  for (int i = 0; i < 8; ++i) {
    ushort4 a0 = *(const ushort4*)(src + i * 8);
    ushort4 a1 = *(const ushort4*)(src + i * 8 + 4);
    float4 f0, f1;
    f0.x = bf2f(a0.x); f0.y = bf2f(a0.y); f0.z = bf2f(a0.z); f0.w = bf2f(a0.w);
    f1.x = bf2f(a1.x); f1.y = bf2f(a1.y); f1.z = bf2f(a1.z); f1.w = bf2f(a1.w);
    *(float4*)(dst + i * 8) = f0;
    *(float4*)(dst + i * 8 + 4) = f1;
  }
}

// ---------------- launcher ----------------
// ws: [0,4MB) Wt | [4MB,+256KB) smap | +40KB sliceBr | +1KB tsArr |
//     [5MB, +WC*640KB) xT | [then, +WC*640KB) oT
extern "C" void kernel_launch(void* const* d_in, const int* in_sizes, int n_in,
                              void* d_out, int out_size, void* d_ws, size_t ws_size,
                              hipStream_t stream) {
  const float* x    = (const float*)d_in[0];
  const int*   bidx = (const int*)d_in[1];
  const float* W    = (const float*)d_in[2];
  const float* bias = (const float*)d_in[3];
  float* out = (float*)d_out;

  char* ws = (char*)d_ws;
  ushort_t* Wt = (ushort_t*)ws;
  unsigned short* smap = (unsigned short*)(ws + (4u << 20));
  int* sliceBr = (int*)(ws + (4u << 20) + 262144);
  int* tsArr   = (int*)(ws + (4u << 20) + 262144 + 40960);

  const size_t perWin = (size_t)NKT * SLCAP * BK * 2;   // 655360 B (xT); oT same size
  size_t avail = ws_size > (5u << 20) ? ws_size - (5u << 20) : 0;
  int WC = 8;
  const int opts[4] = {64, 32, 16, 8};
  for (int i = 0; i < 4; ++i) {
    if ((size_t)opts[i] * perWin * 2 <= avail) { WC = opts[i]; break; }
  }
  ushort_t* xT = (ushort_t*)(ws + (5u << 20));
  ushort_t* oT = (ushort_t*)(ws + (5u << 20) + (size_t)WC * perWin);

  k_wtrans<<<512, 256, 0, stream>>>(W, Wt);
  k_sort<<<NWIN, WIN, 0, stream>>>(bidx, smap, sliceBr, tsArr);
  for (int w0 = 0; w0 < NWIN; w0 += WC) {
    k_xcvt<<<WC * 4, 512, 0, stream>>>(x, smap, xT, w0);
    k_gemm<<<WC * 10, 512, 0, stream>>>(xT, Wt, bias, sliceBr, tsArr, oT, w0);
    k_ocvt<<<WC * 8, 512, 0, stream>>>(oT, smap, out, w0);
  }
}

// Round 10
// 365.623 us; speedup vs baseline: 1.4882x; 1.4882x over previous
//
#include <hip/hip_runtime.h>
#include <hip/hip_bf16.h>
#include <stdint.h>

#define T_TOK 131072
#define DIM   512
#define NBR   8
#define ROWS  128                 // tokens per block (natural order)
#define NBLK  (T_TOK / ROWS)      // 1024
#define BK    32
#define NKT   (DIM / BK)          // 16
#define PLANE_U 4672              // ushorts per kt-plane (144 slots * 32kk + 64 twist pad)
#define MAXSL 16                  // max slices per block is 15

typedef __attribute__((ext_vector_type(8))) __bf16 bf16x8;
typedef __attribute__((ext_vector_type(4))) float  f32x4;
typedef unsigned short ushort_t;

__device__ __forceinline__ unsigned short f2bf(float f) {
  union { float f; unsigned int u; } v; v.f = f;
  unsigned int r = v.u + 0x7fffu + ((v.u >> 16) & 1u);
  return (unsigned short)(r >> 16);
}

// ---------- W transpose: (N,D,D) f32 -> Wt bf16 [b][kt][col][kk] ----------
__global__ __launch_bounds__(256) void k_wtrans(const float* __restrict__ W,
                                                ushort_t* __restrict__ Wt) {
  __shared__ float tile[BK][129];
  int blk = blockIdx.x;          // 8 * 16 * 4 = 512 blocks
  int b  = blk >> 6;
  int kt = (blk >> 2) & 15;
  int cb = blk & 3;
  int t = threadIdx.x;
  #pragma unroll
  for (int i = 0; i < 4; ++i) {
    int idx4 = i * 256 + t;
    int kr = idx4 >> 5;
    int c4 = idx4 & 31;
    const float* src = W + (((size_t)b * DIM + (size_t)(kt * BK + kr)) * DIM + cb * 128 + c4 * 4);
    float4 v = *(const float4*)src;
    tile[kr][c4 * 4 + 0] = v.x;
    tile[kr][c4 * 4 + 1] = v.y;
    tile[kr][c4 * 4 + 2] = v.z;
    tile[kr][c4 * 4 + 3] = v.w;
  }
  __syncthreads();
  int c  = t >> 1;
  int kh = t & 1;
  unsigned int p[8];
  #pragma unroll
  for (int i = 0; i < 8; ++i) {
    unsigned short lo = f2bf(tile[kh * 16 + i * 2 + 0][c]);
    unsigned short hi = f2bf(tile[kh * 16 + i * 2 + 1][c]);
    p[i] = (unsigned int)lo | ((unsigned int)hi << 16);
  }
  size_t obase = (((size_t)b * 16 + kt) * DIM + (size_t)(cb * 128 + c)) * BK + kh * 16;
  uint4 q0; q0.x = p[0]; q0.y = p[1]; q0.z = p[2]; q0.w = p[3];
  uint4 q1; q1.x = p[4]; q1.y = p[5]; q1.z = p[6]; q1.w = p[7];
  *(uint4*)&Wt[obase]     = q0;
  *(uint4*)&Wt[obase + 8] = q1;
}

// ---------- fused: local sort + stage + GEMM + natural-order store ----------
// Block = 128 natural tokens x 512 cols. 8 waves = 2 slice-groups x 4 col-groups(128).
// x read: 512B-chunk sequential within block's 256KB. out write: 64B-granule
// scatter WITHIN block's 256KB window (L2 assembles lines -> sequential drain).
// A-tile LDS swizzled (2 lanes/16B-position -> conflict-free b128 reads).
__global__ __launch_bounds__(512, 2)
void k_fused(const float* __restrict__ x, const int* __restrict__ bidx,
             const ushort_t* __restrict__ Wt, const float* __restrict__ bias,
             float* __restrict__ out) {
  __shared__ ushort_t AT[NKT * PLANE_U];          // 149504 B
  __shared__ int cnt[NBR], pref[NBR];
  __shared__ int sliceBaseL[MAXSL], sliceBrL[MAXSL], slimL[MAXSL];
  __shared__ short slotOfL[ROWS];
  __shared__ short pmapL[ROWS + 16];
  __shared__ int tsL;

  const int t  = threadIdx.x;
  const int l  = t & 63;
  const int li = l & 15;
  const int c2 = l >> 4;
  const int wv = t >> 6;
  const int sgi = wv >> 2;            // slice-group 0..1
  const int cg  = wv & 3;             // col-group (128 cols)
  const int row0 = blockIdx.x * ROWS;

  // ---- local sort ----
  if (t < NBR) cnt[t] = 0;
  __syncthreads();
  int myb = 0, myrank = 0;
  if (t < ROWS) {
    myb = bidx[row0 + t];
    myrank = atomicAdd(&cnt[myb], 1);
  }
  __syncthreads();
  if (t == 0) {
    int s = 0, ns = 0;
    for (int b = 0; b < NBR; ++b) {
      pref[b] = s;
      int c = cnt[b];
      for (int o = 0; o < c; o += 16) {
        sliceBaseL[ns] = s + o; sliceBrL[ns] = b; slimL[ns] = s + c; ++ns;
      }
      s += c;
    }
    tsL = ns;
  }
  __syncthreads();
  if (t < ROWS) {
    int slot = pref[myb] + myrank;
    slotOfL[t] = (short)slot;
    pmapL[slot] = (short)t;
  }
  __syncthreads();
  const int nslice = tsL;

  // ---- per-wave constants ----
  const int boff0 = ((cg << 7) + li) * BK + c2 * 8;   // + cf*512
  const float4* xp4 = (const float4*)(x + (size_t)row0 * DIM);

  // slice regs
  bool slv[4]; int sbrR[4], slimR[4], sbaseR[4], abase[4];
  f32x4 acc[4][8];

  auto load_slices = [&](int p) {
    #pragma unroll
    for (int s = 0; s < 4; ++s) {
      int sl = p * 8 + sgi * 4 + s;
      bool v = sl < nslice;
      slv[s] = v;
      int sb = v ? sliceBaseL[sl] : 0;
      sbrR[s] = v ? sliceBrL[sl] : 0;
      slimR[s] = v ? slimL[sl] : 0;
      sbaseR[s] = sb;
      int slot = sb + li;
      int chp = (c2 | ((slot & 1) << 2)) ^ ((slot >> 1) & 7);
      abase[s] = ((slot >> 1) << 6) + (chp << 3);
    }
  };
  auto zero_acc = [&]() {
    #pragma unroll
    for (int s = 0; s < 4; ++s)
      #pragma unroll
      for (int cf = 0; cf < 8; ++cf) acc[s][cf] = (f32x4){0.f, 0.f, 0.f, 0.f};
  };
  auto computeKT = [&](int kt) {
    int curbr = -1;
    bf16x8 bq[8];
    #pragma unroll
    for (int s = 0; s < 4; ++s) {
      if (slv[s]) {
        if (sbrR[s] != curbr) {
          curbr = sbrR[s];
          const ushort_t* wp = Wt + ((size_t)(curbr * NKT + kt) << 14);
          #pragma unroll
          for (int cf = 0; cf < 8; ++cf) bq[cf] = *(const bf16x8*)(wp + boff0 + cf * 512);
        }
        bf16x8 af = *(const bf16x8*)&AT[abase[s] + kt * PLANE_U + ((kt & 7) << 3)];
        #pragma unroll
        for (int cf = 0; cf < 8; ++cf)
          acc[s][cf] = __builtin_amdgcn_mfma_f32_16x16x32_bf16(af, bq[cf], acc[s][cf], 0, 0, 0);
      }
    }
  };
  auto epilogue = [&]() {
    #pragma unroll
    for (int s = 0; s < 4; ++s) {
      if (!slv[s]) continue;
      const int br = sbrR[s];
      float bv[8];
      #pragma unroll
      for (int cf = 0; cf < 8; ++cf)
        bv[cf] = bias[br * DIM + (cg << 7) + cf * 16 + li];
      #pragma unroll
      for (int j = 0; j < 4; ++j) {
        int slot = sbaseR[s] + c2 * 4 + j;
        if (slot < slimR[s]) {
          int row = pmapL[slot];
          float* op = out + ((size_t)(row0 + row)) * DIM + (cg << 7) + li;
          #pragma unroll
          for (int cf = 0; cf < 8; ++cf) op[cf * 16] = acc[s][cf][j] + bv[cf];
        }
      }
    }
  };

  float4 v[8];
  auto loadq = [&](int q) {
    const float4* base = xp4 + q * 32;
    #pragma unroll
    for (int i = 0; i < 8; ++i) {
      int row = i * 16 + (t >> 5);
      int c = t & 31;
      v[i] = base[row * 128 + c];
    }
  };
  auto writeq = [&](int q) {
    #pragma unroll
    for (int i = 0; i < 8; ++i) {
      int row = i * 16 + (t >> 5);
      int c = t & 31;
      int slot = slotOfL[row];
      int kt = q * 4 + (c >> 3);
      int chunk = (c >> 1) & 3;
      int half = c & 1;
      int chp = (chunk | ((slot & 1) << 2)) ^ ((slot >> 1) & 7);
      int off = kt * PLANE_U + ((kt & 7) << 3) + ((slot >> 1) << 6) + (chp << 3) + (half << 2);
      ushort4 a4;
      a4.x = f2bf(v[i].x); a4.y = f2bf(v[i].y); a4.z = f2bf(v[i].z); a4.w = f2bf(v[i].w);
      *(ushort4*)&AT[off] = a4;
    }
  };

  // ---- pass 0 with kt-quad pipelined staging ----
  load_slices(0);
  zero_acc();
  loadq(0); writeq(0);
  __syncthreads();
  for (int q = 0; q < 4; ++q) {
    if (q < 3) loadq(q + 1);            // issue next quad's x loads early
    #pragma unroll
    for (int k2 = 0; k2 < 4; ++k2) computeKT(q * 4 + k2);
    if (q < 3) { writeq(q + 1); __syncthreads(); }
  }
  epilogue();

  // ---- pass 1 (slices 8..14, present in ~half the blocks) ----
  if (nslice > 8) {
    load_slices(1);
    zero_acc();
    for (int kt = 0; kt < NKT; ++kt) computeKT(kt);
    epilogue();
  }
}

// ---------------- launcher ----------------
// ws: [0,4MB) Wt bf16
extern "C" void kernel_launch(void* const* d_in, const int* in_sizes, int n_in,
                              void* d_out, int out_size, void* d_ws, size_t ws_size,
                              hipStream_t stream) {
  const float* x    = (const float*)d_in[0];
  const int*   bidx = (const int*)d_in[1];
  const float* W    = (const float*)d_in[2];
  const float* bias = (const float*)d_in[3];
  float* out = (float*)d_out;

  ushort_t* Wt = (ushort_t*)d_ws;

  k_wtrans<<<512, 256, 0, stream>>>(W, Wt);
  k_fused<<<NBLK, 512, 0, stream>>>(x, bidx, Wt, bias, out);
}